// Round 1
// baseline (619.484 us; speedup 1.0000x reference)
//
#include <hip/hip_runtime.h>
#include <hip/hip_bf16.h>
#include <stdint.h>

#define DIN   4096
#define DOUT  4096
#define MROWS 8192   // B*S = 4*2048

typedef __bf16 bf16_t;
typedef __attribute__((ext_vector_type(8))) __bf16 bf16x8;
typedef __attribute__((ext_vector_type(4))) float   f32x4;

__device__ __forceinline__ unsigned short f2bf(float f) {
    union { float f; unsigned u; } v; v.f = f;
    unsigned r = v.u + 0x7FFFu + ((v.u >> 16) & 1u);   // RNE
    return (unsigned short)(r >> 16);
}

// ---------------------------------------------------------------------------
// Kernel 1: Wt[n][k] = bf16( base_T[k][n] + c * (2*mask[k][n] - 1) )
// LDS-tiled 32x32 transpose; reads coalesced over n, writes coalesced over k.
// ---------------------------------------------------------------------------
__global__ void build_wt(const float* __restrict__ baseT,
                         const int*   __restrict__ mask,
                         const float* __restrict__ coeff,
                         unsigned short* __restrict__ Wt) {
    __shared__ float tile[32][33];          // +1 pad: conflict-free transpose
    const float c = coeff[0];
    const int tx = threadIdx.x;             // 0..31
    const int ty = threadIdx.y;             // 0..7
    const int n0 = blockIdx.x * 32;
    const int k0 = blockIdx.y * 32;
#pragma unroll
    for (int r = 0; r < 4; ++r) {
        int k = k0 + ty + r * 8;
        int n = n0 + tx;
        size_t idx = (size_t)k * DOUT + n;
        float v = baseT[idx] + c * (float)(2 * mask[idx] - 1);
        tile[ty + r * 8][tx] = v;
    }
    __syncthreads();
#pragma unroll
    for (int r = 0; r < 4; ++r) {
        int n = n0 + ty + r * 8;
        int k = k0 + tx;
        Wt[(size_t)n * DIN + k] = f2bf(tile[tx][ty + r * 8]);
    }
}

// ---------------------------------------------------------------------------
// Kernel 2: x fp32 -> bf16 bits, 8 elements/thread, 16B loads / 8B stores
// ---------------------------------------------------------------------------
__global__ void cvt_x(const float* __restrict__ x, unsigned short* __restrict__ xb) {
    int i = blockIdx.x * 256 + threadIdx.x;
    const float4* xv = (const float4*)x;
    float4 a = xv[2 * i];
    float4 b = xv[2 * i + 1];
    ushort4 o0 = make_ushort4(f2bf(a.x), f2bf(a.y), f2bf(a.z), f2bf(a.w));
    ushort4 o1 = make_ushort4(f2bf(b.x), f2bf(b.y), f2bf(b.z), f2bf(b.w));
    ushort4* ov = (ushort4*)xb;
    ov[2 * i]     = o0;
    ov[2 * i + 1] = o1;
}

// ---------------------------------------------------------------------------
// Kernel 3: out[m][n] = sum_k X[m][k] * Wt[n][k]   (bf16 in, fp32 out)
// m97 structure: 128x128 tile, BK=32, 4 waves as 2x2, 4x4 MFMA 16x16x32 each,
// global_load_lds width=16 staging, 2-barrier K-loop.
// ---------------------------------------------------------------------------
__global__ __launch_bounds__(256, 2)
void gemm_bt(const unsigned short* __restrict__ X,    // [MROWS][DIN] bf16 bits
             const unsigned short* __restrict__ Wt,   // [DOUT][DIN]  bf16 bits
             float* __restrict__ out) {               // [MROWS][DOUT] fp32
    __shared__ __align__(16) bf16_t sA[128 * 32];     // [m][k] 8 KB
    __shared__ __align__(16) bf16_t sB[128 * 32];     // [n][k] 8 KB

    const int tid  = threadIdx.x;
    const int lane = tid & 63;
    const int wv   = tid >> 6;        // 0..3
    const int bm   = blockIdx.x & 63; // 64 m-tiles (fast) -> L3 reuse of Wt
    const int bn   = blockIdx.x >> 6; // 32 n-tiles
    const int wm   = wv >> 1;         // 0..1
    const int wn   = wv & 1;          // 0..1

    // ---- staging addresses: lane l of wave w writes LDS bytes w*2048+i*1024+l*16
    //      => tile row = w*32 + i*16 + l/4, k-offset = (l%4)*8 elements
    const int kcol = (lane & 3) * 8;
    const int row0 = wv * 32 + (lane >> 2);
    const unsigned short* gA0 = X  + (size_t)(bm * 128 + row0) * DIN + kcol;
    const unsigned short* gA1 = gA0 + 16 * DIN;
    const unsigned short* gB0 = Wt + (size_t)(bn * 128 + row0) * DIN + kcol;
    const unsigned short* gB1 = gB0 + 16 * DIN;
    bf16_t* lA0 = sA + wv * 1024;
    bf16_t* lA1 = sA + wv * 1024 + 512;
    bf16_t* lB0 = sB + wv * 1024;
    bf16_t* lB1 = sB + wv * 1024 + 512;

    // ---- fragment read offsets (A: m=lane&15,k=(lane>>4)*8+j ; B dual)
    const int arow = wm * 64 + (lane & 15);
    const int brow = wn * 64 + (lane & 15);
    const int koff = (lane >> 4) * 8;

    f32x4 acc[4][4];
#pragma unroll
    for (int i = 0; i < 4; ++i)
#pragma unroll
        for (int j = 0; j < 4; ++j) acc[i][j] = (f32x4){0.f, 0.f, 0.f, 0.f};

    for (int kt = 0; kt < DIN / 32; ++kt) {
        __builtin_amdgcn_global_load_lds((const __attribute__((address_space(1))) void*)gA0,
                                         (__attribute__((address_space(3))) void*)lA0, 16, 0, 0);
        __builtin_amdgcn_global_load_lds((const __attribute__((address_space(1))) void*)gA1,
                                         (__attribute__((address_space(3))) void*)lA1, 16, 0, 0);
        __builtin_amdgcn_global_load_lds((const __attribute__((address_space(1))) void*)gB0,
                                         (__attribute__((address_space(3))) void*)lB0, 16, 0, 0);
        __builtin_amdgcn_global_load_lds((const __attribute__((address_space(1))) void*)gB1,
                                         (__attribute__((address_space(3))) void*)lB1, 16, 0, 0);
        gA0 += 32; gA1 += 32; gB0 += 32; gB1 += 32;
        __syncthreads();   // drains vmcnt(0): tiles resident

        bf16x8 af[4], bf[4];
#pragma unroll
        for (int mi = 0; mi < 4; ++mi)
            af[mi] = *(const bf16x8*)&sA[(arow + mi * 16) * 32 + koff];
#pragma unroll
        for (int ni = 0; ni < 4; ++ni)
            bf[ni] = *(const bf16x8*)&sB[(brow + ni * 16) * 32 + koff];
#pragma unroll
        for (int mi = 0; mi < 4; ++mi)
#pragma unroll
            for (int ni = 0; ni < 4; ++ni)
                acc[mi][ni] = __builtin_amdgcn_mfma_f32_16x16x32_bf16(
                    af[mi], bf[ni], acc[mi][ni], 0, 0, 0);
        __syncthreads();   // all waves done reading before next stage
    }

    // ---- epilogue: D row = (lane>>4)*4 + r, col = lane&15
    const int crow0 = bm * 128 + wm * 64 + (lane >> 4) * 4;
    const int ccol0 = bn * 128 + wn * 64 + (lane & 15);
#pragma unroll
    for (int mi = 0; mi < 4; ++mi)
#pragma unroll
        for (int ni = 0; ni < 4; ++ni)
#pragma unroll
            for (int r = 0; r < 4; ++r)
                out[(size_t)(crow0 + mi * 16 + r) * DOUT + (ccol0 + ni * 16)] =
                    acc[mi][ni][r];
}

extern "C" void kernel_launch(void* const* d_in, const int* in_sizes, int n_in,
                              void* d_out, int out_size, void* d_ws, size_t ws_size,
                              hipStream_t stream) {
    const float* x     = (const float*)d_in[0];
    const float* baseT = (const float*)d_in[1];
    const int*   mask  = (const int*)d_in[2];
    const float* coeff = (const float*)d_in[3];

    unsigned short* Wt = (unsigned short*)d_ws;                              // 32 MB
    unsigned short* Xb = (unsigned short*)((char*)d_ws + (size_t)DIN * DOUT * 2); // 64 MB
    float* out = (float*)d_out;

    dim3 bA(32, 8);
    dim3 gA(DOUT / 32, DIN / 32);
    build_wt<<<gA, bA, 0, stream>>>(baseT, mask, coeff, Wt);

    cvt_x<<<(MROWS * DIN / 8) / 256, 256, 0, stream>>>(x, Xb);

    gemm_bt<<<64 * 32, 256, 0, stream>>>(Xb, Wt, out);
}